// Round 1
// baseline (1384.049 us; speedup 1.0000x reference)
//
#include <hip/hip_runtime.h>
#include <math.h>

#define NH    12
#define BB    2
#define SEQ   2048
#define DMODEL 768
#define DK    64

// ---------------------------------------------------------------------------
// GEMM: C = A[M,Kd] @ W[N,Kd]^T   (torch Linear convention)
// Tile 64x64, BK=16, 256 threads, 4x4 micro-tile per thread.
// SPLIT_HEADS: write C in (B, H, S, DK) layout instead of row-major (M, N).
// ---------------------------------------------------------------------------
template<bool SPLIT_HEADS>
__global__ __launch_bounds__(256) void gemm_nt(const float* __restrict__ A,
                                               const float* __restrict__ W,
                                               float* __restrict__ C,
                                               int M, int N, int Kd) {
    const int tid = threadIdx.x;
    const int tx = tid & 15;        // 0..15 -> output cols tx*4..tx*4+3
    const int ty = tid >> 4;        // 0..15 -> output rows ty*4..ty*4+3
    const int n0 = blockIdx.x * 64;
    const int m0 = blockIdx.y * 64;

    __shared__ float As[64][17];    // +1 pad: breaks 4-way bank conflict on row reads
    __shared__ float Ws[64][17];

    float acc[4][4] = {};

    const int lr = tid >> 2;          // 0..63 load row
    const int lc = (tid & 3) * 4;     // 0,4,8,12 load col

    for (int k0 = 0; k0 < Kd; k0 += 16) {
        __syncthreads();
        {
            const float4 av = *(const float4*)(A + (size_t)(m0 + lr) * Kd + k0 + lc);
            As[lr][lc + 0] = av.x; As[lr][lc + 1] = av.y;
            As[lr][lc + 2] = av.z; As[lr][lc + 3] = av.w;
            const float4 wv = *(const float4*)(W + (size_t)(n0 + lr) * Kd + k0 + lc);
            Ws[lr][lc + 0] = wv.x; Ws[lr][lc + 1] = wv.y;
            Ws[lr][lc + 2] = wv.z; Ws[lr][lc + 3] = wv.w;
        }
        __syncthreads();
        #pragma unroll
        for (int kk = 0; kk < 16; ++kk) {
            float a[4], b[4];
            #pragma unroll
            for (int i = 0; i < 4; ++i) a[i] = As[ty * 4 + i][kk];
            #pragma unroll
            for (int j = 0; j < 4; ++j) b[j] = Ws[tx * 4 + j][kk];
            #pragma unroll
            for (int i = 0; i < 4; ++i)
                #pragma unroll
                for (int j = 0; j < 4; ++j)
                    acc[i][j] = fmaf(a[i], b[j], acc[i][j]);
        }
    }

    if (SPLIT_HEADS) {
        // n0 is a multiple of 64 == DK, so the whole tile is one head
        const int h = n0 / DK;
        #pragma unroll
        for (int i = 0; i < 4; ++i) {
            const int m = m0 + ty * 4 + i;
            const int b = m / SEQ;
            const int s = m % SEQ;
            float* op = C + (((size_t)b * NH + h) * SEQ + s) * DK + tx * 4;
            float4 v = make_float4(acc[i][0], acc[i][1], acc[i][2], acc[i][3]);
            *(float4*)op = v;
        }
    } else {
        #pragma unroll
        for (int i = 0; i < 4; ++i) {
            const int m = m0 + ty * 4 + i;
            float* op = C + (size_t)m * N + n0 + tx * 4;
            float4 v = make_float4(acc[i][0], acc[i][1], acc[i][2], acc[i][3]);
            *(float4*)op = v;
        }
    }
}

// ---------------------------------------------------------------------------
// Flash attention (causal). One block per (b, h, 64-query tile).
// 256 threads; thread (ty,tx) owns rows ty*4..+3 (queries), cols tx*4..+3.
// K and V share one LDS buffer (sequenced by barriers). Online softmax.
// ---------------------------------------------------------------------------
__global__ __launch_bounds__(256) void flash_attn(const float* __restrict__ q,
                                                  const float* __restrict__ k,
                                                  const float* __restrict__ v,
                                                  float* __restrict__ ctx) {
    const int tid = threadIdx.x;
    const int tx = tid & 15;
    const int ty = tid >> 4;
    const int q0 = blockIdx.x * 64;
    const int h  = blockIdx.y;
    const int b  = blockIdx.z;

    const float* qp = q + ((size_t)b * NH + h) * SEQ * DK;
    const float* kp = k + ((size_t)b * NH + h) * SEQ * DK;
    const float* vp = v + ((size_t)b * NH + h) * SEQ * DK;

    // pad to 68 (multiple of 4 floats) -> rows stay 16B aligned for float4 LDS ops
    __shared__ __align__(16) float Qs[64][68];
    __shared__ __align__(16) float KVs[64][68];
    __shared__ __align__(16) float Ps[64][68];
    __shared__ float m_s[64], l_s[64], alpha_s[64];

    // load Q tile (64 x 64)
    for (int i = tid; i < 64 * 16; i += 256) {
        const int r = i >> 4, c = (i & 15) * 4;
        float4 t = *(const float4*)(qp + (size_t)(q0 + r) * DK + c);
        *(float4*)&Qs[r][c] = t;
    }
    if (tid < 64) { m_s[tid] = -INFINITY; l_s[tid] = 0.f; }

    float o[4][4] = {};
    const float scale = 0.125f;   // 1/sqrt(64)
    const int nkt = q0 / 64 + 1;  // causal: key tiles 0..q0/64

    for (int kt = 0; kt < nkt; ++kt) {
        const int k0 = kt * 64;
        __syncthreads();   // prev-iter PV reads of KVs/Ps done; Qs ready (iter 0)

        for (int i = tid; i < 64 * 16; i += 256) {
            const int r = i >> 4, c = (i & 15) * 4;
            float4 t = *(const float4*)(kp + (size_t)(k0 + r) * DK + c);
            *(float4*)&KVs[r][c] = t;
        }
        __syncthreads();

        // scores: sc[i][j] = Q[q0+ty*4+i] . K[k0+tx*4+j]
        float sc[4][4] = {};
        #pragma unroll
        for (int d4 = 0; d4 < 16; ++d4) {
            float qv[4][4], kv[4][4];
            #pragma unroll
            for (int i = 0; i < 4; ++i) {
                float4 t = *(const float4*)&Qs[ty * 4 + i][d4 * 4];
                qv[i][0] = t.x; qv[i][1] = t.y; qv[i][2] = t.z; qv[i][3] = t.w;
            }
            #pragma unroll
            for (int j = 0; j < 4; ++j) {
                float4 t = *(const float4*)&KVs[tx * 4 + j][d4 * 4];
                kv[j][0] = t.x; kv[j][1] = t.y; kv[j][2] = t.z; kv[j][3] = t.w;
            }
            #pragma unroll
            for (int i = 0; i < 4; ++i)
                #pragma unroll
                for (int j = 0; j < 4; ++j)
                    #pragma unroll
                    for (int t = 0; t < 4; ++t)
                        sc[i][j] = fmaf(qv[i][t], kv[j][t], sc[i][j]);
        }

        // causal mask + write score tile
        #pragma unroll
        for (int i = 0; i < 4; ++i)
            #pragma unroll
            for (int j = 0; j < 4; ++j) {
                float s = sc[i][j] * scale;
                if (k0 + tx * 4 + j > q0 + ty * 4 + i) s = -1e9f;
                Ps[ty * 4 + i][tx * 4 + j] = s;
            }
        __syncthreads();

        // load V into the same buffer (KVs is free now); overlap with softmax
        for (int i = tid; i < 64 * 16; i += 256) {
            const int r = i >> 4, c = (i & 15) * 4;
            float4 t = *(const float4*)(vp + (size_t)(k0 + r) * DK + c);
            *(float4*)&KVs[r][c] = t;
        }

        // online softmax, one thread per query row
        if (tid < 64) {
            const int r = tid;
            const float mold = m_s[r];
            float mx = mold;
            for (int c = 0; c < 64; ++c) mx = fmaxf(mx, Ps[r][c]);
            const float alpha = __expf(mold - mx);
            float sum = 0.f;
            for (int c = 0; c < 64; ++c) {
                float p = __expf(Ps[r][c] - mx);
                Ps[r][c] = p;
                sum += p;
            }
            m_s[r] = mx;
            l_s[r] = l_s[r] * alpha + sum;
            alpha_s[r] = alpha;
        }
        __syncthreads();

        // O = O*alpha + P @ V
        #pragma unroll
        for (int i = 0; i < 4; ++i) {
            const float al = alpha_s[ty * 4 + i];
            #pragma unroll
            for (int j = 0; j < 4; ++j) o[i][j] *= al;
        }
        #pragma unroll
        for (int kk4 = 0; kk4 < 16; ++kk4) {
            float pv[4][4], vv[4][4];
            #pragma unroll
            for (int i = 0; i < 4; ++i) {
                float4 t = *(const float4*)&Ps[ty * 4 + i][kk4 * 4];
                pv[i][0] = t.x; pv[i][1] = t.y; pv[i][2] = t.z; pv[i][3] = t.w;
            }
            #pragma unroll
            for (int t = 0; t < 4; ++t) {
                float4 tv = *(const float4*)&KVs[kk4 * 4 + t][tx * 4];
                vv[t][0] = tv.x; vv[t][1] = tv.y; vv[t][2] = tv.z; vv[t][3] = tv.w;
            }
            #pragma unroll
            for (int i = 0; i < 4; ++i)
                #pragma unroll
                for (int j = 0; j < 4; ++j)
                    #pragma unroll
                    for (int t = 0; t < 4; ++t)
                        o[i][j] = fmaf(pv[i][t], vv[t][j], o[i][j]);
        }
    }

    // finalize: divide by l, write ctx in (B, S, D) layout
    #pragma unroll
    for (int i = 0; i < 4; ++i) {
        const float inv = 1.f / l_s[ty * 4 + i];
        const int s = q0 + ty * 4 + i;
        float* op = ctx + ((size_t)b * SEQ + s) * DMODEL + h * DK + tx * 4;
        float4 val = make_float4(o[i][0] * inv, o[i][1] * inv, o[i][2] * inv, o[i][3] * inv);
        *(float4*)op = val;
    }
}

// ---------------------------------------------------------------------------
extern "C" void kernel_launch(void* const* d_in, const int* in_sizes, int n_in,
                              void* d_out, int out_size, void* d_ws, size_t ws_size,
                              hipStream_t stream) {
    const float* Q  = (const float*)d_in[0];
    const float* K  = (const float*)d_in[1];
    const float* V  = (const float*)d_in[2];
    // d_in[3] = mask (causal, known statically -> unused)
    const float* Wq = (const float*)d_in[4];
    const float* Wk = (const float*)d_in[5];
    const float* Wv = (const float*)d_in[6];
    const float* Wo = (const float*)d_in[7];

    const size_t per = (size_t)BB * NH * SEQ * DK;   // 3,145,728 floats
    float* ws = (float*)d_ws;
    float* qb = ws;
    float* kb = ws + per;
    float* vb = ws + 2 * per;
    float* cb = ws + 3 * per;                        // ctx, (B, S, D)

    const int M = BB * SEQ;        // 4096
    const int N = DMODEL;          // 768
    const int Kd = DMODEL;         // 768

    dim3 blk(256);
    dim3 gg(N / 64, M / 64, 1);    // (12, 64)

    gemm_nt<true><<<gg, blk, 0, stream>>>(Q, Wq, qb, M, N, Kd);
    gemm_nt<true><<<gg, blk, 0, stream>>>(K, Wk, kb, M, N, Kd);
    gemm_nt<true><<<gg, blk, 0, stream>>>(V, Wv, vb, M, N, Kd);

    dim3 ga(SEQ / 64, NH, BB);     // (32, 12, 2)
    flash_attn<<<ga, blk, 0, stream>>>(qb, kb, vb, cb);

    gemm_nt<false><<<gg, blk, 0, stream>>>(cb, Wo, (float*)d_out, M, N, Kd);
}

// Round 2
// 257.385 us; speedup vs baseline: 5.3774x; 5.3774x over previous
//
#include <hip/hip_runtime.h>
#include <math.h>

#define NH     12
#define BB     2
#define SEQ    2048
#define DMODEL 768
#define DK     64

typedef __attribute__((ext_vector_type(8))) short short8;   // 8 bf16 = 4 VGPRs
typedef __attribute__((ext_vector_type(4))) float floatx4;  // MFMA acc

__device__ __forceinline__ unsigned short f2bf(float x) {
    unsigned u = __builtin_bit_cast(unsigned, x);
    u = (u + 0x7fffu + ((u >> 16) & 1u)) >> 16;   // round-to-nearest-even
    return (unsigned short)u;
}
__device__ __forceinline__ float bf2f(unsigned short h) {
    unsigned u = ((unsigned)h) << 16;
    return __builtin_bit_cast(float, u);
}

// ---------------------------------------------------------------------------
// cast fp32 -> bf16 for the 3 inputs and 4 weights. blockIdx.z picks array.
// ---------------------------------------------------------------------------
__global__ __launch_bounds__(256) void cast_all(
    const float* __restrict__ Q, const float* __restrict__ K, const float* __restrict__ V,
    const float* __restrict__ Wq, const float* __restrict__ Wk, const float* __restrict__ Wv,
    const float* __restrict__ Wo,
    ushort* oQ, ushort* oK, ushort* oV, ushort* oWq, ushort* oWk, ushort* oWv, ushort* oWo) {
    const float* src; ushort* dst; int n;
    switch (blockIdx.z) {
        case 0: src = Q;  dst = oQ;  n = BB * SEQ * DMODEL; break;
        case 1: src = K;  dst = oK;  n = BB * SEQ * DMODEL; break;
        case 2: src = V;  dst = oV;  n = BB * SEQ * DMODEL; break;
        case 3: src = Wq; dst = oWq; n = DMODEL * DMODEL;   break;
        case 4: src = Wk; dst = oWk; n = DMODEL * DMODEL;   break;
        case 5: src = Wv; dst = oWv; n = DMODEL * DMODEL;   break;
        default: src = Wo; dst = oWo; n = DMODEL * DMODEL;  break;
    }
    int i4 = (blockIdx.x * 256 + threadIdx.x) * 4;
    if (i4 < n) {
        float4 v = *(const float4*)(src + i4);
        ushort4 o;
        o.x = f2bf(v.x); o.y = f2bf(v.y); o.z = f2bf(v.z); o.w = f2bf(v.w);
        *(ushort4*)(dst + i4) = o;
    }
}

// ---------------------------------------------------------------------------
// bf16 MFMA GEMM: C = A[M,768] @ W[768,768]^T  (W row-major [N][K] -> B^T input)
// 128x128 tile, BK=64, 4 waves (2x2), each wave 64x64 via 4x4 16x16x32 MFMAs.
// MODE 0: fp32 out row-major [M,768].  MODE 1: bf16 out split-head (b,h,s,dk)*scale.
// ---------------------------------------------------------------------------
template<int MODE>
__device__ __forceinline__ void gemm_body(const ushort* __restrict__ A,
                                          const ushort* __restrict__ W,
                                          float* __restrict__ outF,
                                          ushort* __restrict__ outH,
                                          float scale) {
    const int n0 = blockIdx.x * 128;
    const int m0 = blockIdx.y * 128;
    const int tid  = threadIdx.x;
    const int lane = tid & 63;
    const int wv   = tid >> 6;
    const int l15  = lane & 15;
    const int quad = lane >> 4;
    const int wm = (wv >> 1) * 64;
    const int wn = (wv & 1) * 64;

    __shared__ ushort As [128 * 64];
    __shared__ ushort Ws2[128 * 64];

    floatx4 acc[4][4];
    #pragma unroll
    for (int i = 0; i < 4; ++i)
        #pragma unroll
        for (int j = 0; j < 4; ++j) acc[i][j] = (floatx4)0.f;

    for (int k0 = 0; k0 < DMODEL; k0 += 64) {
        __syncthreads();
        #pragma unroll
        for (int it = 0; it < 4; ++it) {
            const int row  = (tid >> 3) + it * 32;
            const int col8 = (tid & 7) * 8;
            *(int4*)&As [row * 64 + col8] = *(const int4*)(A + (size_t)(m0 + row) * DMODEL + k0 + col8);
            *(int4*)&Ws2[row * 64 + col8] = *(const int4*)(W + (size_t)(n0 + row) * DMODEL + k0 + col8);
        }
        __syncthreads();
        #pragma unroll
        for (int kc = 0; kc < 2; ++kc) {
            short8 af[4], bf[4];
            #pragma unroll
            for (int mi = 0; mi < 4; ++mi)
                af[mi] = *(const short8*)&As[(wm + mi * 16 + l15) * 64 + kc * 32 + quad * 8];
            #pragma unroll
            for (int ni = 0; ni < 4; ++ni)
                bf[ni] = *(const short8*)&Ws2[(wn + ni * 16 + l15) * 64 + kc * 32 + quad * 8];
            #pragma unroll
            for (int mi = 0; mi < 4; ++mi)
                #pragma unroll
                for (int ni = 0; ni < 4; ++ni)
                    acc[mi][ni] = __builtin_amdgcn_mfma_f32_16x16x32_bf16(af[mi], bf[ni], acc[mi][ni], 0, 0, 0);
        }
    }

    #pragma unroll
    for (int mi = 0; mi < 4; ++mi)
        #pragma unroll
        for (int ni = 0; ni < 4; ++ni)
            #pragma unroll
            for (int r = 0; r < 4; ++r) {
                const int m = m0 + wm + mi * 16 + quad * 4 + r;
                const int n = n0 + wn + ni * 16 + l15;
                const float v = acc[mi][ni][r] * scale;
                if (MODE == 0) {
                    outF[(size_t)m * DMODEL + n] = v;
                } else {
                    const int b = m >> 11, s = m & (SEQ - 1);
                    const int h = n >> 6,  dk = n & 63;
                    outH[(((size_t)b * NH + h) * SEQ + s) * DK + dk] = f2bf(v);
                }
            }
}

__global__ __launch_bounds__(256) void gemm_qkv(
    const ushort* Qb, const ushort* Kb, const ushort* Vb,
    const ushort* Wqb, const ushort* Wkb, const ushort* Wvb,
    ushort* qh, ushort* kh, ushort* vh) {
    const int z = blockIdx.z;
    const ushort* A = (z == 0) ? Qb : (z == 1) ? Kb : Vb;
    const ushort* W = (z == 0) ? Wqb : (z == 1) ? Wkb : Wvb;
    ushort* out     = (z == 0) ? qh : (z == 1) ? kh : vh;
    const float scale = (z == 0) ? 0.125f : 1.0f;   // fold 1/sqrt(dk) into Q (exact)
    gemm_body<1>(A, W, nullptr, out, scale);
}

__global__ __launch_bounds__(256) void gemm_out(const ushort* A, const ushort* W, float* out) {
    gemm_body<0>(A, W, out, nullptr, 1.0f);
}

// ---------------------------------------------------------------------------
// transpose V heads: (b,h,s,dk) -> (b,h,dk,s), bf16. fp32 LDS tile kills conflicts.
// ---------------------------------------------------------------------------
__global__ __launch_bounds__(256) void transpose_v(const ushort* __restrict__ vh,
                                                   ushort* __restrict__ vhT) {
    const int bh = blockIdx.y;
    const int s0 = blockIdx.x * 64;
    __shared__ float T[64][65];
    const int t = threadIdx.x;
    {
        const int row = t >> 2, c16 = (t & 3) * 16;
        const ushort* src = vh + ((size_t)bh * SEQ + s0 + row) * DK + c16;
        short8 v0 = *(const short8*)(src);
        short8 v1 = *(const short8*)(src + 8);
        #pragma unroll
        for (int i = 0; i < 8; ++i) {
            T[row][c16 + i]     = bf2f((unsigned short)v0[i]);
            T[row][c16 + 8 + i] = bf2f((unsigned short)v1[i]);
        }
    }
    __syncthreads();
    {
        const int dk = t >> 2, sc = (t & 3) * 16;
        short8 o0, o1;
        #pragma unroll
        for (int i = 0; i < 8; ++i) {
            o0[i] = (short)f2bf(T[sc + i][dk]);
            o1[i] = (short)f2bf(T[sc + 8 + i][dk]);
        }
        ushort* dst = vhT + ((size_t)bh * DK + dk) * SEQ + s0 + sc;
        *(short8*)(dst)     = o0;
        *(short8*)(dst + 8) = o1;
    }
}

// ---------------------------------------------------------------------------
// MFMA flash attention (causal). Block = (b,h,64-query tile), 4 waves.
// Wave owns 16 query rows. Q frags in registers; K and V^T tiles in LDS.
// Online softmax fully in registers via shuffles; P->LDS (wave-private) for PV.
// 1/sqrt(dk) already folded into q. Writes ctx bf16 (B,S,D).
// ---------------------------------------------------------------------------
__global__ __launch_bounds__(256) void flash_mfma(const ushort* __restrict__ qh,
                                                  const ushort* __restrict__ kh,
                                                  const ushort* __restrict__ vhT,
                                                  ushort* __restrict__ ctx) {
    const int bh = blockIdx.x;                 // 0..23
    const int b  = bh / NH, h = bh % NH;
    const int qt = (gridDim.y - 1) - blockIdx.y;  // heaviest tiles dispatch first
    const int q0 = qt * 64;

    const int tid  = threadIdx.x;
    const int lane = tid & 63;
    const int wv   = tid >> 6;
    const int l15  = lane & 15;
    const int quad = lane >> 4;

    __shared__ ushort Ks [64 * 64];
    __shared__ ushort Vts[64 * 64];
    __shared__ ushort Ps[4][16 * 72];          // per-wave P tile, stride 72 (16B-aligned rows)

    // Q fragment: A-layout, rows q0 + wv*16 + l15, k-chunks of 32
    short8 q_frag[2];
    {
        const ushort* qp = qh + ((size_t)bh * SEQ + q0 + wv * 16 + l15) * DK;
        q_frag[0] = *(const short8*)(qp + quad * 8);
        q_frag[1] = *(const short8*)(qp + 32 + quad * 8);
    }

    float m_r[4], l_r[4];
    floatx4 o_acc[4];
    #pragma unroll
    for (int r = 0; r < 4; ++r) { m_r[r] = -3.0e38f; l_r[r] = 0.f; }
    #pragma unroll
    for (int d = 0; d < 4; ++d) o_acc[d] = (floatx4)0.f;

    for (int kt = 0; kt <= qt; ++kt) {
        const int k0 = kt * 64;
        __syncthreads();    // prev iter's LDS reads done
        #pragma unroll
        for (int it = 0; it < 2; ++it) {
            const int row  = (tid >> 3) + it * 32;
            const int col8 = (tid & 7) * 8;
            *(int4*)&Ks [row * 64 + col8] = *(const int4*)(kh  + ((size_t)bh * SEQ + k0 + row) * DK + col8);
            *(int4*)&Vts[row * 64 + col8] = *(const int4*)(vhT + ((size_t)bh * DK + row) * SEQ + k0 + col8);
        }
        __syncthreads();

        // S = q . K^T : 16 queries x 64 keys per wave
        floatx4 s_acc[4];
        #pragma unroll
        for (int nt = 0; nt < 4; ++nt) s_acc[nt] = (floatx4)0.f;
        #pragma unroll
        for (int kc = 0; kc < 2; ++kc)
            #pragma unroll
            for (int nt = 0; nt < 4; ++nt) {
                short8 kf = *(const short8*)&Ks[(nt * 16 + l15) * 64 + kc * 32 + quad * 8];
                s_acc[nt] = __builtin_amdgcn_mfma_f32_16x16x32_bf16(q_frag[kc], kf, s_acc[nt], 0, 0, 0);
            }

        // causal mask (diagonal tile only)
        if (kt == qt) {
            #pragma unroll
            for (int nt = 0; nt < 4; ++nt)
                #pragma unroll
                for (int r = 0; r < 4; ++r) {
                    const int col  = nt * 16 + l15;
                    const int rowl = wv * 16 + quad * 4 + r;
                    if (col > rowl) s_acc[nt][r] = -1.0e30f;
                }
        }

        // online softmax (rows = quad*4+r, cols across nt and the quad's 16 lanes)
        float alpha[4];
        #pragma unroll
        for (int r = 0; r < 4; ++r) {
            float mx = fmaxf(fmaxf(s_acc[0][r], s_acc[1][r]), fmaxf(s_acc[2][r], s_acc[3][r]));
            #pragma unroll
            for (int d = 1; d < 16; d <<= 1) mx = fmaxf(mx, __shfl_xor(mx, d));
            const float mnew = fmaxf(m_r[r], mx);
            alpha[r] = __expf(m_r[r] - mnew);
            m_r[r] = mnew;
            float rs = 0.f;
            #pragma unroll
            for (int nt = 0; nt < 4; ++nt) {
                const float p = __expf(s_acc[nt][r] - mnew);
                s_acc[nt][r] = p;
                rs += p;
            }
            #pragma unroll
            for (int d = 1; d < 16; d <<= 1) rs += __shfl_xor(rs, d);
            l_r[r] = l_r[r] * alpha[r] + rs;
        }
        #pragma unroll
        for (int d = 0; d < 4; ++d)
            #pragma unroll
            for (int r = 0; r < 4; ++r) o_acc[d][r] *= alpha[r];

        // P -> LDS (wave-private region; in-wave lgkmcnt ordering suffices)
        #pragma unroll
        for (int nt = 0; nt < 4; ++nt)
            #pragma unroll
            for (int r = 0; r < 4; ++r)
                Ps[wv][(quad * 4 + r) * 72 + nt * 16 + l15] = f2bf(s_acc[nt][r]);

        // O += P @ V
        #pragma unroll
        for (int kc = 0; kc < 2; ++kc) {
            short8 pf = *(const short8*)&Ps[wv][l15 * 72 + kc * 32 + quad * 8];
            #pragma unroll
            for (int dkt = 0; dkt < 4; ++dkt) {
                short8 vf = *(const short8*)&Vts[(dkt * 16 + l15) * 64 + kc * 32 + quad * 8];
                o_acc[dkt] = __builtin_amdgcn_mfma_f32_16x16x32_bf16(pf, vf, o_acc[dkt], 0, 0, 0);
            }
        }
    }

    // finalize and write ctx (B, S, D) bf16
    #pragma unroll
    for (int r = 0; r < 4; ++r) {
        const float inv = 1.f / l_r[r];
        const int s = q0 + wv * 16 + quad * 4 + r;
        #pragma unroll
        for (int dkt = 0; dkt < 4; ++dkt) {
            const int d = h * DK + dkt * 16 + l15;
            ctx[((size_t)b * SEQ + s) * DMODEL + d] = f2bf(o_acc[dkt][r] * inv);
        }
    }
}

// ---------------------------------------------------------------------------
extern "C" void kernel_launch(void* const* d_in, const int* in_sizes, int n_in,
                              void* d_out, int out_size, void* d_ws, size_t ws_size,
                              hipStream_t stream) {
    const float* Q  = (const float*)d_in[0];
    const float* K  = (const float*)d_in[1];
    const float* V  = (const float*)d_in[2];
    const float* Wq = (const float*)d_in[4];
    const float* Wk = (const float*)d_in[5];
    const float* Wv = (const float*)d_in[6];
    const float* Wo = (const float*)d_in[7];

    char* ws = (char*)d_ws;
    const size_t SZ_IN = (size_t)BB * SEQ * DMODEL * 2;   // 6,291,456 B
    const size_t SZ_W  = (size_t)DMODEL * DMODEL * 2;     // 1,179,648 B
    ushort* Qbf = (ushort*)(ws);
    ushort* Kbf = (ushort*)(ws + SZ_IN);
    ushort* Vbf = (ushort*)(ws + 2 * SZ_IN);
    ushort* Wqb = (ushort*)(ws + 3 * SZ_IN);
    ushort* Wkb = (ushort*)(ws + 3 * SZ_IN + SZ_W);
    ushort* Wvb = (ushort*)(ws + 3 * SZ_IN + 2 * SZ_W);
    ushort* Wob = (ushort*)(ws + 3 * SZ_IN + 3 * SZ_W);
    ushort* qh  = (ushort*)(ws + 3 * SZ_IN + 4 * SZ_W);
    ushort* kh  = (ushort*)(ws + 4 * SZ_IN + 4 * SZ_W);
    ushort* vh  = (ushort*)(ws + 5 * SZ_IN + 4 * SZ_W);
    ushort* vhT = Kbf;   // Kbf dead after gemm_qkv
    ushort* ctx = Qbf;   // Qbf dead after gemm_qkv

    dim3 blk(256);
    cast_all<<<dim3(3072, 1, 7), blk, 0, stream>>>(Q, K, V, Wq, Wk, Wv, Wo,
                                                   Qbf, Kbf, Vbf, Wqb, Wkb, Wvb, Wob);
    gemm_qkv<<<dim3(6, 32, 3), blk, 0, stream>>>(Qbf, Kbf, Vbf, Wqb, Wkb, Wvb, qh, kh, vh);
    transpose_v<<<dim3(32, 24), blk, 0, stream>>>(vh, vhT);
    flash_mfma<<<dim3(24, 32), blk, 0, stream>>>(qh, kh, vhT, ctx);
    gemm_out<<<dim3(6, 32), blk, 0, stream>>>(ctx, Wob, (float*)d_out);
}

// Round 3
// 232.177 us; speedup vs baseline: 5.9612x; 1.1086x over previous
//
#include <hip/hip_runtime.h>
#include <math.h>

#define NH     12
#define BB     2
#define SEQ    2048
#define DMODEL 768
#define DK     64

typedef __attribute__((ext_vector_type(8))) short short8;   // 8 bf16 = 4 VGPRs
typedef __attribute__((ext_vector_type(4))) float floatx4;  // MFMA acc

__device__ __forceinline__ unsigned short f2bf(float x) {
    unsigned u = __builtin_bit_cast(unsigned, x);
    u = (u + 0x7fffu + ((u >> 16) & 1u)) >> 16;   // round-to-nearest-even
    return (unsigned short)u;
}
__device__ __forceinline__ unsigned short f2bf_fast(float x) {
    // round-to-nearest (ties away). safe for finite |x| < ~3.4e38
    unsigned u = __builtin_bit_cast(unsigned, x);
    return (unsigned short)((u + 0x8000u) >> 16);
}
__device__ __forceinline__ float bf2f(unsigned short h) {
    unsigned u = ((unsigned)h) << 16;
    return __builtin_bit_cast(float, u);
}

// async global -> LDS, 16 bytes per lane. LDS dest must be wave-uniform base + lane*16.
__device__ __forceinline__ void gld_lds16(const ushort* gptr, ushort* lptr) {
    __builtin_amdgcn_global_load_lds(
        (const __attribute__((address_space(1))) unsigned int*)(const void*)gptr,
        (__attribute__((address_space(3))) unsigned int*)(void*)lptr,
        16, 0, 0);
}

// ---------------------------------------------------------------------------
// cast fp32 -> bf16, flat 1D grid. Segment sizes are multiples of 1024 so each
// 256-thread block (1024 elements) stays within one segment -> uniform branch.
// ---------------------------------------------------------------------------
#define SI (BB * SEQ * DMODEL)     // 3,145,728
#define SW (DMODEL * DMODEL)       //   589,824

__global__ __launch_bounds__(256) void cast_all(
    const float* __restrict__ Q, const float* __restrict__ K, const float* __restrict__ V,
    const float* __restrict__ Wq, const float* __restrict__ Wk, const float* __restrict__ Wv,
    const float* __restrict__ Wo,
    ushort* oQ, ushort* oK, ushort* oV, ushort* oWq, ushort* oWk, ushort* oWv, ushort* oWo) {
    long i = (long)(blockIdx.x * 256 + threadIdx.x) * 4;
    const float* src; ushort* dst; long off;
    if      (i < 1L * SI)          { src = Q;  dst = oQ;  off = i; }
    else if (i < 2L * SI)          { src = K;  dst = oK;  off = i - 1L * SI; }
    else if (i < 3L * SI)          { src = V;  dst = oV;  off = i - 2L * SI; }
    else if (i < 3L * SI + SW)     { src = Wq; dst = oWq; off = i - 3L * SI; }
    else if (i < 3L * SI + 2L*SW)  { src = Wk; dst = oWk; off = i - 3L * SI - SW; }
    else if (i < 3L * SI + 3L*SW)  { src = Wv; dst = oWv; off = i - 3L * SI - 2L * SW; }
    else                           { src = Wo; dst = oWo; off = i - 3L * SI - 3L * SW; }
    float4 v = *(const float4*)(src + off);
    ushort4 o;
    o.x = f2bf(v.x); o.y = f2bf(v.y); o.z = f2bf(v.z); o.w = f2bf(v.w);
    *(ushort4*)(dst + off) = o;
}

// ---------------------------------------------------------------------------
// bf16 MFMA GEMM: C = A[M,768] @ W[768,768]^T.  128x128 tile, BK=64, 4 waves,
// double-buffered LDS via global_load_lds, ONE barrier per K-step.
// MODE 0: fp32 out row-major.  MODE 1: bf16 out split-head (b,h,s,dk) * scale.
// ---------------------------------------------------------------------------
template<int MODE>
__device__ __forceinline__ void gemm_body(const ushort* __restrict__ A,
                                          const ushort* __restrict__ W,
                                          float* __restrict__ outF,
                                          ushort* __restrict__ outH,
                                          float scale) {
    const int n0 = blockIdx.x * 128;
    const int m0 = blockIdx.y * 128;
    const int tid  = threadIdx.x;
    const int lane = tid & 63;
    const int wv   = tid >> 6;
    const int l15  = lane & 15;
    const int quad = lane >> 4;
    const int wm = (wv >> 1) * 64;
    const int wn = (wv & 1) * 64;

    __shared__ ushort S[2][2][128 * 64];   // [buf][A/W] = 64 KB

    const int srow = tid >> 3;             // 0..31
    const int scol = (tid & 7) * 8;        // shorts (16 B)

    floatx4 acc[4][4];
    #pragma unroll
    for (int i = 0; i < 4; ++i)
        #pragma unroll
        for (int j = 0; j < 4; ++j) acc[i][j] = (floatx4)0.f;

    // prologue: tile 0 -> buf 0
    #pragma unroll
    for (int it = 0; it < 4; ++it) {
        const int r = srow + it * 32;
        gld_lds16(A + (size_t)(m0 + r) * DMODEL + scol, &S[0][0][r * 64 + scol]);
        gld_lds16(W + (size_t)(n0 + r) * DMODEL + scol, &S[0][1][r * 64 + scol]);
    }

    for (int t = 0; t < DMODEL / 64; ++t) {
        __syncthreads();                    // drains this tile's loads + ends prev compute
        if (t + 1 < DMODEL / 64) {
            const int k0 = (t + 1) * 64;
            const int bi = (t + 1) & 1;
            #pragma unroll
            for (int it = 0; it < 4; ++it) {
                const int r = srow + it * 32;
                gld_lds16(A + (size_t)(m0 + r) * DMODEL + k0 + scol, &S[bi][0][r * 64 + scol]);
                gld_lds16(W + (size_t)(n0 + r) * DMODEL + k0 + scol, &S[bi][1][r * 64 + scol]);
            }
        }
        const ushort* As  = S[t & 1][0];
        const ushort* Ws2 = S[t & 1][1];
        #pragma unroll
        for (int kc = 0; kc < 2; ++kc) {
            short8 af[4], bf[4];
            #pragma unroll
            for (int mi = 0; mi < 4; ++mi)
                af[mi] = *(const short8*)&As[(wm + mi * 16 + l15) * 64 + kc * 32 + quad * 8];
            #pragma unroll
            for (int ni = 0; ni < 4; ++ni)
                bf[ni] = *(const short8*)&Ws2[(wn + ni * 16 + l15) * 64 + kc * 32 + quad * 8];
            #pragma unroll
            for (int mi = 0; mi < 4; ++mi)
                #pragma unroll
                for (int ni = 0; ni < 4; ++ni)
                    acc[mi][ni] = __builtin_amdgcn_mfma_f32_16x16x32_bf16(af[mi], bf[ni], acc[mi][ni], 0, 0, 0);
        }
    }

    #pragma unroll
    for (int mi = 0; mi < 4; ++mi)
        #pragma unroll
        for (int ni = 0; ni < 4; ++ni)
            #pragma unroll
            for (int r = 0; r < 4; ++r) {
                const int m = m0 + wm + mi * 16 + quad * 4 + r;
                const int n = n0 + wn + ni * 16 + l15;
                const float v = acc[mi][ni][r] * scale;
                if (MODE == 0) {
                    outF[(size_t)m * DMODEL + n] = v;
                } else {
                    const int b = m >> 11, s = m & (SEQ - 1);
                    const int h = n >> 6,  dk = n & 63;
                    outH[(((size_t)b * NH + h) * SEQ + s) * DK + dk] = f2bf(v);
                }
            }
}

// scale for Q: 1/sqrt(64) * log2(e) -> softmax uses exp2 directly
#define QSCALE (0.125f * 1.44269504088896f)

__global__ __launch_bounds__(256) void gemm_qkv(
    const ushort* Qb, const ushort* Kb, const ushort* Vb,
    const ushort* Wqb, const ushort* Wkb, const ushort* Wvb,
    ushort* qh, ushort* kh, ushort* vh) {
    const int z = blockIdx.z;
    const ushort* A = (z == 0) ? Qb : (z == 1) ? Kb : Vb;
    const ushort* W = (z == 0) ? Wqb : (z == 1) ? Wkb : Wvb;
    ushort* out     = (z == 0) ? qh : (z == 1) ? kh : vh;
    const float scale = (z == 0) ? QSCALE : 1.0f;
    gemm_body<1>(A, W, nullptr, out, scale);
}

__global__ __launch_bounds__(256) void gemm_out(const ushort* A, const ushort* W, float* out) {
    gemm_body<0>(A, W, out, nullptr, 1.0f);
}

// ---------------------------------------------------------------------------
// transpose V heads: (b,h,s,dk) -> (b,h,dk,s), bf16 via fp32 LDS tile.
// ---------------------------------------------------------------------------
__global__ __launch_bounds__(256) void transpose_v(const ushort* __restrict__ vh,
                                                   ushort* __restrict__ vhT) {
    const int bh = blockIdx.y;
    const int s0 = blockIdx.x * 64;
    __shared__ float T[64][65];
    const int t = threadIdx.x;
    {
        const int row = t >> 2, c16 = (t & 3) * 16;
        const ushort* src = vh + ((size_t)bh * SEQ + s0 + row) * DK + c16;
        short8 v0 = *(const short8*)(src);
        short8 v1 = *(const short8*)(src + 8);
        #pragma unroll
        for (int i = 0; i < 8; ++i) {
            T[row][c16 + i]     = bf2f((unsigned short)v0[i]);
            T[row][c16 + 8 + i] = bf2f((unsigned short)v1[i]);
        }
    }
    __syncthreads();
    {
        const int dk = t >> 2, sc = (t & 3) * 16;
        short8 o0, o1;
        #pragma unroll
        for (int i = 0; i < 8; ++i) {
            o0[i] = (short)f2bf(T[sc + i][dk]);
            o1[i] = (short)f2bf(T[sc + 8 + i][dk]);
        }
        ushort* dst = vhT + ((size_t)bh * DK + dk) * SEQ + s0 + sc;
        *(short8*)(dst)     = o0;
        *(short8*)(dst + 8) = o1;
    }
}

// ---------------------------------------------------------------------------
// MFMA flash attention (causal). Block = (b,h,64-query tile), 4 waves, wave=16 rows.
// Double-buffered K/V^T via global_load_lds, ONE barrier per k-tile (prefetch
// issued before compute -> vmcnt drain at the barrier is free).
// log2e/sqrt(dk) pre-folded into q -> softmax uses exp2. Writes ctx bf16 (B,S,D).
// ---------------------------------------------------------------------------
__global__ __launch_bounds__(256) void flash_mfma(const ushort* __restrict__ qh,
                                                  const ushort* __restrict__ kh,
                                                  const ushort* __restrict__ vhT,
                                                  ushort* __restrict__ ctx) {
    const int bh = blockIdx.x;                    // 0..23
    const int b  = bh / NH, h = bh % NH;
    const int qt = (gridDim.y - 1) - blockIdx.y;  // heaviest tiles first
    const int q0 = qt * 64;

    const int tid  = threadIdx.x;
    const int lane = tid & 63;
    const int wv   = tid >> 6;
    const int l15  = lane & 15;
    const int quad = lane >> 4;

    __shared__ ushort KV[2][2][64 * 64];          // [buf][K / V^T] = 32 KB
    __shared__ ushort Ps[4][16 * 72];             // per-wave P tile

    const ushort* kbase = kh  + (size_t)bh * SEQ * DK;
    const ushort* vbase = vhT + (size_t)bh * DK * SEQ;

    const int srow = tid >> 3;                    // 0..31
    const int scol = (tid & 7) * 8;               // shorts

    // Q fragment (A-layout): rows q0 + wv*16 + l15
    short8 q_frag[2];
    {
        const ushort* qp = qh + ((size_t)bh * SEQ + q0 + wv * 16 + l15) * DK;
        q_frag[0] = *(const short8*)(qp + quad * 8);
        q_frag[1] = *(const short8*)(qp + 32 + quad * 8);
    }

    // prologue: tile 0 -> buf 0
    {
        gld_lds16(kbase + (size_t)(srow) * DK + scol,            &KV[0][0][srow * 64 + scol]);
        gld_lds16(kbase + (size_t)(srow + 32) * DK + scol,       &KV[0][0][(srow + 32) * 64 + scol]);
        gld_lds16(vbase + (size_t)srow * SEQ + scol,             &KV[0][1][srow * 64 + scol]);
        gld_lds16(vbase + (size_t)(srow + 32) * SEQ + scol,      &KV[0][1][(srow + 32) * 64 + scol]);
    }

    float m_r[4], l_r[4];
    floatx4 o_acc[4];
    #pragma unroll
    for (int r = 0; r < 4; ++r) { m_r[r] = -3.0e38f; l_r[r] = 0.f; }
    #pragma unroll
    for (int d = 0; d < 4; ++d) o_acc[d] = (floatx4)0.f;

    for (int kt = 0; kt <= qt; ++kt) {
        __syncthreads();   // drains tile-kt loads (in flight during prev compute) + syncs buffers
        if (kt < qt) {
            const int k0 = (kt + 1) * 64;
            const int bi = (kt + 1) & 1;
            gld_lds16(kbase + (size_t)(k0 + srow) * DK + scol,        &KV[bi][0][srow * 64 + scol]);
            gld_lds16(kbase + (size_t)(k0 + srow + 32) * DK + scol,   &KV[bi][0][(srow + 32) * 64 + scol]);
            gld_lds16(vbase + (size_t)srow * SEQ + k0 + scol,         &KV[bi][1][srow * 64 + scol]);
            gld_lds16(vbase + (size_t)(srow + 32) * SEQ + k0 + scol,  &KV[bi][1][(srow + 32) * 64 + scol]);
        }
        const ushort* Ks  = KV[kt & 1][0];
        const ushort* Vts = KV[kt & 1][1];

        // S = q . K^T : 16 queries x 64 keys per wave
        floatx4 s_acc[4];
        #pragma unroll
        for (int nt = 0; nt < 4; ++nt) s_acc[nt] = (floatx4)0.f;
        #pragma unroll
        for (int kc = 0; kc < 2; ++kc)
            #pragma unroll
            for (int nt = 0; nt < 4; ++nt) {
                short8 kf = *(const short8*)&Ks[(nt * 16 + l15) * 64 + kc * 32 + quad * 8];
                s_acc[nt] = __builtin_amdgcn_mfma_f32_16x16x32_bf16(q_frag[kc], kf, s_acc[nt], 0, 0, 0);
            }

        // causal mask (diagonal tile only)
        if (kt == qt) {
            #pragma unroll
            for (int nt = 0; nt < 4; ++nt)
                #pragma unroll
                for (int r = 0; r < 4; ++r) {
                    const int col  = nt * 16 + l15;
                    const int rowl = wv * 16 + quad * 4 + r;
                    if (col > rowl) s_acc[nt][r] = -1.0e30f;
                }
        }

        // online softmax in log2 domain
        float alpha[4];
        #pragma unroll
        for (int r = 0; r < 4; ++r) {
            float mx = fmaxf(fmaxf(s_acc[0][r], s_acc[1][r]), fmaxf(s_acc[2][r], s_acc[3][r]));
            #pragma unroll
            for (int d = 1; d < 16; d <<= 1) mx = fmaxf(mx, __shfl_xor(mx, d));
            const float mnew = fmaxf(m_r[r], mx);
            alpha[r] = exp2f(m_r[r] - mnew);
            m_r[r] = mnew;
            float rs = 0.f;
            #pragma unroll
            for (int nt = 0; nt < 4; ++nt) {
                const float p = exp2f(s_acc[nt][r] - mnew);
                s_acc[nt][r] = p;
                rs += p;
            }
            #pragma unroll
            for (int d = 1; d < 16; d <<= 1) rs += __shfl_xor(rs, d);
            l_r[r] = l_r[r] * alpha[r] + rs;
        }
        #pragma unroll
        for (int d = 0; d < 4; ++d)
            #pragma unroll
            for (int r = 0; r < 4; ++r) o_acc[d][r] *= alpha[r];

        // P -> LDS (wave-private; in-wave lgkm ordering suffices, no barrier)
        #pragma unroll
        for (int nt = 0; nt < 4; ++nt)
            #pragma unroll
            for (int r = 0; r < 4; ++r)
                Ps[wv][(quad * 4 + r) * 72 + nt * 16 + l15] = f2bf_fast(s_acc[nt][r]);

        // O += P @ V
        #pragma unroll
        for (int kc = 0; kc < 2; ++kc) {
            short8 pf = *(const short8*)&Ps[wv][l15 * 72 + kc * 32 + quad * 8];
            #pragma unroll
            for (int dkt = 0; dkt < 4; ++dkt) {
                short8 vf = *(const short8*)&Vts[(dkt * 16 + l15) * 64 + kc * 32 + quad * 8];
                o_acc[dkt] = __builtin_amdgcn_mfma_f32_16x16x32_bf16(pf, vf, o_acc[dkt], 0, 0, 0);
            }
        }
    }

    // finalize and write ctx (B, S, D) bf16
    #pragma unroll
    for (int r = 0; r < 4; ++r) {
        const float inv = 1.f / l_r[r];
        const int s = q0 + wv * 16 + quad * 4 + r;
        #pragma unroll
        for (int dkt = 0; dkt < 4; ++dkt) {
            const int d = h * DK + dkt * 16 + l15;
            ctx[((size_t)b * SEQ + s) * DMODEL + d] = f2bf(o_acc[dkt][r] * inv);
        }
    }
}

// ---------------------------------------------------------------------------
extern "C" void kernel_launch(void* const* d_in, const int* in_sizes, int n_in,
                              void* d_out, int out_size, void* d_ws, size_t ws_size,
                              hipStream_t stream) {
    const float* Q  = (const float*)d_in[0];
    const float* K  = (const float*)d_in[1];
    const float* V  = (const float*)d_in[2];
    const float* Wq = (const float*)d_in[4];
    const float* Wk = (const float*)d_in[5];
    const float* Wv = (const float*)d_in[6];
    const float* Wo = (const float*)d_in[7];

    char* ws = (char*)d_ws;
    const size_t SZ_IN = (size_t)SI * 2;
    const size_t SZ_W  = (size_t)SW * 2;
    ushort* Qbf = (ushort*)(ws);
    ushort* Kbf = (ushort*)(ws + SZ_IN);
    ushort* Vbf = (ushort*)(ws + 2 * SZ_IN);
    ushort* Wqb = (ushort*)(ws + 3 * SZ_IN);
    ushort* Wkb = (ushort*)(ws + 3 * SZ_IN + SZ_W);
    ushort* Wvb = (ushort*)(ws + 3 * SZ_IN + 2 * SZ_W);
    ushort* Wob = (ushort*)(ws + 3 * SZ_IN + 3 * SZ_W);
    ushort* qh  = (ushort*)(ws + 3 * SZ_IN + 4 * SZ_W);
    ushort* kh  = (ushort*)(ws + 4 * SZ_IN + 4 * SZ_W);
    ushort* vh  = (ushort*)(ws + 5 * SZ_IN + 4 * SZ_W);
    ushort* vhT = Kbf;   // Kbf dead after gemm_qkv
    ushort* ctx = Qbf;   // Qbf dead after gemm_qkv

    dim3 blk(256);
    // (3*SI + 4*SW) / 4 / 256 = 11,520 blocks
    cast_all<<<dim3((3 * SI + 4 * SW) / 1024), blk, 0, stream>>>(
        Q, K, V, Wq, Wk, Wv, Wo, Qbf, Kbf, Vbf, Wqb, Wkb, Wvb, Wob);
    gemm_qkv<<<dim3(6, 32, 3), blk, 0, stream>>>(Qbf, Kbf, Vbf, Wqb, Wkb, Wvb, qh, kh, vh);
    transpose_v<<<dim3(32, 24), blk, 0, stream>>>(vh, vhT);
    flash_mfma<<<dim3(24, 32), blk, 0, stream>>>(qh, kh, vhT, ctx);
    gemm_out<<<dim3(6, 32), blk, 0, stream>>>(ctx, Wob, (float*)d_out);
}

// Round 4
// 227.871 us; speedup vs baseline: 6.0738x; 1.0189x over previous
//
#include <hip/hip_runtime.h>
#include <math.h>

#define NH     12
#define BB     2
#define SEQ    2048
#define DMODEL 768
#define DK     64

typedef __attribute__((ext_vector_type(8))) short short8;   // 8 bf16 = 4 VGPRs
typedef __attribute__((ext_vector_type(4))) short short4v;  // 4 bf16 = 8 B
typedef __attribute__((ext_vector_type(4))) float floatx4;  // MFMA acc

__device__ __forceinline__ unsigned short f2bf(float x) {
    unsigned u = __builtin_bit_cast(unsigned, x);
    u = (u + 0x7fffu + ((u >> 16) & 1u)) >> 16;   // round-to-nearest-even
    return (unsigned short)u;
}
__device__ __forceinline__ unsigned short f2bf_fast(float x) {
    unsigned u = __builtin_bit_cast(unsigned, x);
    return (unsigned short)((u + 0x8000u) >> 16);
}

// async global -> LDS, 16 B per lane. Dest is wave-uniform base + lane*16.
__device__ __forceinline__ void gld_lds16(const ushort* gptr, ushort* lptr) {
    __builtin_amdgcn_global_load_lds(
        (const __attribute__((address_space(1))) unsigned int*)(const void*)gptr,
        (__attribute__((address_space(3))) unsigned int*)(void*)lptr,
        16, 0, 0);
}

#define SI (BB * SEQ * DMODEL)     // 3,145,728
#define SW (DMODEL * DMODEL)       //   589,824

// ---------------------------------------------------------------------------
__global__ __launch_bounds__(256) void cast_all(
    const float* __restrict__ Q, const float* __restrict__ K, const float* __restrict__ V,
    const float* __restrict__ Wq, const float* __restrict__ Wk, const float* __restrict__ Wv,
    const float* __restrict__ Wo,
    ushort* oQ, ushort* oK, ushort* oV, ushort* oWq, ushort* oWk, ushort* oWv, ushort* oWo) {
    long i = (long)(blockIdx.x * 256 + threadIdx.x) * 4;
    const float* src; ushort* dst; long off;
    if      (i < 1L * SI)          { src = Q;  dst = oQ;  off = i; }
    else if (i < 2L * SI)          { src = K;  dst = oK;  off = i - 1L * SI; }
    else if (i < 3L * SI)          { src = V;  dst = oV;  off = i - 2L * SI; }
    else if (i < 3L * SI + SW)     { src = Wq; dst = oWq; off = i - 3L * SI; }
    else if (i < 3L * SI + 2L*SW)  { src = Wk; dst = oWk; off = i - 3L * SI - SW; }
    else if (i < 3L * SI + 3L*SW)  { src = Wv; dst = oWv; off = i - 3L * SI - 2L * SW; }
    else                           { src = Wo; dst = oWo; off = i - 3L * SI - 3L * SW; }
    float4 v = *(const float4*)(src + off);
    ushort4 o;
    o.x = f2bf(v.x); o.y = f2bf(v.y); o.z = f2bf(v.z); o.w = f2bf(v.w);
    *(ushort4*)(dst + off) = o;
}

// ---------------------------------------------------------------------------
// bf16 MFMA GEMM: C = A[M,768] @ W[768,768]^T.  128x128 tile, BK=32 double-buffered
// (32 KB LDS -> all 576 blocks co-resident), XOR-swizzled LDS, 1 barrier/step.
// MODE 0: fp32 out row-major.  MODE 1: bf16 out split-head (b,h,s,dk) * scale.
// MODE 2: bf16 out TRANSPOSED split-head (b,h,dk,s) via MFMA operand swap.
// ---------------------------------------------------------------------------
template<int MODE>
__device__ __forceinline__ void gemm_body(const ushort* __restrict__ A,
                                          const ushort* __restrict__ W,
                                          float* __restrict__ outF,
                                          ushort* __restrict__ outH,
                                          float scale) {
    const int n0 = blockIdx.x * 128;
    const int m0 = blockIdx.y * 128;
    const int tid  = threadIdx.x;
    const int lane = tid & 63;
    const int wv   = tid >> 6;
    const int l15  = lane & 15;
    const int quad = lane >> 4;
    const int wm = (wv >> 1) * 64;
    const int wn = (wv & 1) * 64;

    __shared__ __align__(16) ushort S[2][2][128 * 32];   // [buf][A/W] = 32 KB

    const int srow = tid >> 2;                   // 0..63
    const int sch  = tid & 3;                    // dest chunk (8 shorts)
    const int schx = sch ^ ((srow >> 1) & 3);    // swizzled source chunk
    const int sw2  = (l15 >> 1) & 3;             // read-side swizzle term

    floatx4 acc[4][4];
    #pragma unroll
    for (int i = 0; i < 4; ++i)
        #pragma unroll
        for (int j = 0; j < 4; ++j) acc[i][j] = (floatx4)0.f;

    // prologue: step 0 -> buf 0
    #pragma unroll
    for (int it = 0; it < 2; ++it) {
        const int r = srow + it * 64;
        gld_lds16(A + (size_t)(m0 + r) * DMODEL + schx * 8, &S[0][0][r * 32 + sch * 8]);
        gld_lds16(W + (size_t)(n0 + r) * DMODEL + schx * 8, &S[0][1][r * 32 + sch * 8]);
    }

    for (int t = 0; t < DMODEL / 32; ++t) {
        __syncthreads();
        if (t + 1 < DMODEL / 32) {
            const int k0 = (t + 1) * 32;
            const int bi = (t + 1) & 1;
            #pragma unroll
            for (int it = 0; it < 2; ++it) {
                const int r = srow + it * 64;
                gld_lds16(A + (size_t)(m0 + r) * DMODEL + k0 + schx * 8, &S[bi][0][r * 32 + sch * 8]);
                gld_lds16(W + (size_t)(n0 + r) * DMODEL + k0 + schx * 8, &S[bi][1][r * 32 + sch * 8]);
            }
        }
        const ushort* As  = S[t & 1][0];
        const ushort* Ws2 = S[t & 1][1];
        short8 af[4], bf[4];
        #pragma unroll
        for (int mi = 0; mi < 4; ++mi)
            af[mi] = *(const short8*)&As[(wm + mi * 16 + l15) * 32 + ((quad ^ sw2) * 8)];
        #pragma unroll
        for (int ni = 0; ni < 4; ++ni)
            bf[ni] = *(const short8*)&Ws2[(wn + ni * 16 + l15) * 32 + ((quad ^ sw2) * 8)];
        #pragma unroll
        for (int mi = 0; mi < 4; ++mi)
            #pragma unroll
            for (int ni = 0; ni < 4; ++ni) {
                if (MODE == 2)
                    acc[mi][ni] = __builtin_amdgcn_mfma_f32_16x16x32_bf16(bf[ni], af[mi], acc[mi][ni], 0, 0, 0);
                else
                    acc[mi][ni] = __builtin_amdgcn_mfma_f32_16x16x32_bf16(af[mi], bf[ni], acc[mi][ni], 0, 0, 0);
            }
    }

    #pragma unroll
    for (int mi = 0; mi < 4; ++mi)
        #pragma unroll
        for (int ni = 0; ni < 4; ++ni)
            #pragma unroll
            for (int r = 0; r < 4; ++r) {
                const float v = acc[mi][ni][r] * scale;
                if (MODE == 2) {
                    // C[m'=feature][n'=seq]: row=quad*4+r -> feature, col=l15 -> seq
                    const int m = m0 + wm + mi * 16 + l15;          // seq dim
                    const int n = n0 + wn + ni * 16 + quad * 4 + r; // feature dim
                    const int b = m >> 11, s = m & (SEQ - 1);
                    const int h = n >> 6,  dk = n & 63;
                    outH[(((size_t)b * NH + h) * DK + dk) * SEQ + s] = f2bf(v);
                } else {
                    const int m = m0 + wm + mi * 16 + quad * 4 + r;
                    const int n = n0 + wn + ni * 16 + l15;
                    if (MODE == 0) {
                        outF[(size_t)m * DMODEL + n] = v;
                    } else {
                        const int b = m >> 11, s = m & (SEQ - 1);
                        const int h = n >> 6,  dk = n & 63;
                        outH[(((size_t)b * NH + h) * SEQ + s) * DK + dk] = f2bf(v);
                    }
                }
            }
}

// scale for Q: 1/sqrt(64) * log2(e) -> softmax uses exp2 directly
#define QSCALE (0.125f * 1.44269504088896f)

__global__ __launch_bounds__(256) void gemm_qkv(
    const ushort* Qb, const ushort* Kb, const ushort* Vb,
    const ushort* Wqb, const ushort* Wkb, const ushort* Wvb,
    ushort* qh, ushort* kh, ushort* vhT) {
    const int z = blockIdx.z;
    if (z == 0)      gemm_body<1>(Qb, Wqb, nullptr, qh,  QSCALE);
    else if (z == 1) gemm_body<1>(Kb, Wkb, nullptr, kh,  1.0f);
    else             gemm_body<2>(Vb, Wvb, nullptr, vhT, 1.0f);
}

__global__ __launch_bounds__(256) void gemm_out(const ushort* A, const ushort* W, float* out) {
    gemm_body<0>(A, W, out, nullptr, 1.0f);
}

// ---------------------------------------------------------------------------
// MFMA flash attention (causal), work-stealing shells. Item = (bh, 64-q-tile).
// QK^T computed TRANSPOSED (C[key][query]) so the key-reduce is in-lane + 2
// cross-quad shuffles. K/V^T double-buffered via swizzled global_load_lds.
// log2e/sqrt(dk) pre-folded into q. Writes ctx bf16 (B,S,D).
// ---------------------------------------------------------------------------
#define NITEMS (24 * 32)

__global__ __launch_bounds__(256) void flash_mfma(const ushort* __restrict__ qh,
                                                  const ushort* __restrict__ kh,
                                                  const ushort* __restrict__ vhT,
                                                  ushort* __restrict__ ctx,
                                                  int* __restrict__ counter) {
    const int tid  = threadIdx.x;
    const int lane = tid & 63;
    const int wv   = tid >> 6;
    const int l15  = lane & 15;
    const int quad = lane >> 4;

    __shared__ __align__(16) ushort KV[2][2][64 * 64];   // [buf][K / V^T] = 32 KB
    __shared__ __align__(16) ushort Ps[4][16 * 72];      // per-wave P tile (A-layout)
    __shared__ int wshare;

    const int srow = tid >> 3;                 // 0..31
    const int sch  = tid & 7;                  // dest chunk (8 shorts)
    const int schx = sch ^ (srow & 7);         // swizzled source chunk
    const int swq  = l15 & 7;                  // read-side swizzle term

    for (;;) {
        if (tid == 0) wshare = atomicAdd(counter, 1);
        __syncthreads();                        // publishes wshare; ends prev item's LDS use
        const int w = wshare;
        if (w >= NITEMS) break;
        const int qt = 31 - (w / 24);           // heavy items first
        const int bh = w - (w / 24) * 24;
        const int b  = bh / NH, h = bh % NH;
        const int q0 = qt * 64;

        const ushort* kbase = kh  + (size_t)bh * SEQ * DK;
        const ushort* vbase = vhT + (size_t)bh * DK * SEQ;

        // Q fragment (B-operand layout): query = wv*16 + l15
        short8 q_frag[2];
        {
            const ushort* qp = qh + ((size_t)bh * SEQ + q0 + wv * 16 + l15) * DK;
            q_frag[0] = *(const short8*)(qp + quad * 8);
            q_frag[1] = *(const short8*)(qp + 32 + quad * 8);
        }

        // prologue: tile 0 -> buf 0
        gld_lds16(kbase + (size_t)srow * DK + schx * 8,        &KV[0][0][srow * 64 + sch * 8]);
        gld_lds16(kbase + (size_t)(srow + 32) * DK + schx * 8, &KV[0][0][(srow + 32) * 64 + sch * 8]);
        gld_lds16(vbase + (size_t)srow * SEQ + schx * 8,       &KV[0][1][srow * 64 + sch * 8]);
        gld_lds16(vbase + (size_t)(srow + 32) * SEQ + schx * 8,&KV[0][1][(srow + 32) * 64 + sch * 8]);

        float m_s = -3.0e38f, l_s = 0.f;        // per-lane: query = wv*16 + l15
        floatx4 o_acc[4];
        #pragma unroll
        for (int d = 0; d < 4; ++d) o_acc[d] = (floatx4)0.f;

        for (int kt = 0; kt <= qt; ++kt) {
            __syncthreads();                    // drains tile-kt loads
            if (kt < qt) {
                const int k0 = (kt + 1) * 64;
                const int bi = (kt + 1) & 1;
                gld_lds16(kbase + (size_t)(k0 + srow) * DK + schx * 8,        &KV[bi][0][srow * 64 + sch * 8]);
                gld_lds16(kbase + (size_t)(k0 + srow + 32) * DK + schx * 8,   &KV[bi][0][(srow + 32) * 64 + sch * 8]);
                gld_lds16(vbase + (size_t)srow * SEQ + k0 + schx * 8,         &KV[bi][1][srow * 64 + sch * 8]);
                gld_lds16(vbase + (size_t)(srow + 32) * SEQ + k0 + schx * 8,  &KV[bi][1][(srow + 32) * 64 + sch * 8]);
            }
            const ushort* Ks  = KV[kt & 1][0];
            const ushort* Vts = KV[kt & 1][1];

            // S^T = K . q^T : C[key = nt*16 + quad*4 + r][query = l15]
            floatx4 s_acc[4];
            #pragma unroll
            for (int nt = 0; nt < 4; ++nt) s_acc[nt] = (floatx4)0.f;
            #pragma unroll
            for (int kc = 0; kc < 2; ++kc)
                #pragma unroll
                for (int nt = 0; nt < 4; ++nt) {
                    short8 kf = *(const short8*)&Ks[(nt * 16 + l15) * 64 + (((kc * 4 + quad) ^ swq) * 8)];
                    s_acc[nt] = __builtin_amdgcn_mfma_f32_16x16x32_bf16(kf, q_frag[kc], s_acc[nt], 0, 0, 0);
                }

            // causal mask (diagonal tile): key_local > query_local
            if (kt == qt) {
                const int ql = wv * 16 + l15;
                #pragma unroll
                for (int nt = 0; nt < 4; ++nt)
                    #pragma unroll
                    for (int r = 0; r < 4; ++r)
                        if (nt * 16 + quad * 4 + r > ql) s_acc[nt][r] = -1.0e30f;
            }

            // online softmax: key-reduce = in-lane (16 vals) + 2 cross-quad shuffles
            float mx = s_acc[0][0];
            #pragma unroll
            for (int nt = 0; nt < 4; ++nt)
                #pragma unroll
                for (int r = 0; r < 4; ++r) mx = fmaxf(mx, s_acc[nt][r]);
            mx = fmaxf(mx, __shfl_xor(mx, 16));
            mx = fmaxf(mx, __shfl_xor(mx, 32));
            const float mnew = fmaxf(m_s, mx);
            const float al = exp2f(m_s - mnew);
            m_s = mnew;
            float rs = 0.f;
            #pragma unroll
            for (int nt = 0; nt < 4; ++nt) {
                short4v pk;
                #pragma unroll
                for (int r = 0; r < 4; ++r) {
                    const float p = exp2f(s_acc[nt][r] - mnew);
                    rs += p;
                    pk[r] = (short)f2bf_fast(p);
                }
                // Ps A-layout: [query = l15][key = nt*16 + quad*4 + r]
                *(short4v*)&Ps[wv][l15 * 72 + nt * 16 + quad * 4] = pk;
            }
            rs += __shfl_xor(rs, 16);
            rs += __shfl_xor(rs, 32);
            l_s = l_s * al + rs;

            // alpha for O rows (query = wv*16 + quad*4 + r): fetch from lane l15 = quad*4+r
            #pragma unroll
            for (int r = 0; r < 4; ++r) {
                const float ar = __shfl(al, quad * 20 + r);
                #pragma unroll
                for (int d = 0; d < 4; ++d) o_acc[d][r] *= ar;
            }

            // O += P @ V  (pf: A-layout m=query l15; vf: B-layout n=dk l15)
            #pragma unroll
            for (int kc = 0; kc < 2; ++kc) {
                short8 pf = *(const short8*)&Ps[wv][l15 * 72 + kc * 32 + quad * 8];
                #pragma unroll
                for (int dkt = 0; dkt < 4; ++dkt) {
                    short8 vf = *(const short8*)&Vts[(dkt * 16 + l15) * 64 + (((kc * 4 + quad) ^ swq) * 8)];
                    o_acc[dkt] = __builtin_amdgcn_mfma_f32_16x16x32_bf16(pf, vf, o_acc[dkt], 0, 0, 0);
                }
            }
        }

        // finalize: O rows = q0 + wv*16 + quad*4 + r, cols dk = dkt*16 + l15
        #pragma unroll
        for (int r = 0; r < 4; ++r) {
            const float lr = __shfl(l_s, quad * 20 + r);
            const float inv = 1.f / lr;
            const int s = q0 + wv * 16 + quad * 4 + r;
            #pragma unroll
            for (int dkt = 0; dkt < 4; ++dkt) {
                const int d = h * DK + dkt * 16 + l15;
                ctx[((size_t)b * SEQ + s) * DMODEL + d] = f2bf(o_acc[dkt][r] * inv);
            }
        }
    }
}

// ---------------------------------------------------------------------------
extern "C" void kernel_launch(void* const* d_in, const int* in_sizes, int n_in,
                              void* d_out, int out_size, void* d_ws, size_t ws_size,
                              hipStream_t stream) {
    const float* Q  = (const float*)d_in[0];
    const float* K  = (const float*)d_in[1];
    const float* V  = (const float*)d_in[2];
    const float* Wq = (const float*)d_in[4];
    const float* Wk = (const float*)d_in[5];
    const float* Wv = (const float*)d_in[6];
    const float* Wo = (const float*)d_in[7];

    char* ws = (char*)d_ws;
    const size_t SZ_IN = (size_t)SI * 2;
    const size_t SZ_W  = (size_t)SW * 2;
    ushort* Qbf = (ushort*)(ws);
    ushort* Kbf = (ushort*)(ws + SZ_IN);
    ushort* Vbf = (ushort*)(ws + 2 * SZ_IN);
    ushort* Wqb = (ushort*)(ws + 3 * SZ_IN);
    ushort* Wkb = (ushort*)(ws + 3 * SZ_IN + SZ_W);
    ushort* Wvb = (ushort*)(ws + 3 * SZ_IN + 2 * SZ_W);
    ushort* Wob = (ushort*)(ws + 3 * SZ_IN + 3 * SZ_W);
    ushort* qh  = (ushort*)(ws + 3 * SZ_IN + 4 * SZ_W);
    ushort* kh  = (ushort*)(ws + 4 * SZ_IN + 4 * SZ_W);
    ushort* vhT = (ushort*)(ws + 5 * SZ_IN + 4 * SZ_W);
    int*    ctr = (int*)   (ws + 6 * SZ_IN + 4 * SZ_W);
    ushort* ctx = Qbf;   // Qbf dead after gemm_qkv

    dim3 blk(256);
    cast_all<<<dim3((3 * SI + 4 * SW) / 1024), blk, 0, stream>>>(
        Q, K, V, Wq, Wk, Wv, Wo, Qbf, Kbf, Vbf, Wqb, Wkb, Wvb, Wob);
    hipMemsetAsync(ctr, 0, sizeof(int), stream);
    gemm_qkv<<<dim3(6, 32, 3), blk, 0, stream>>>(Qbf, Kbf, Vbf, Wqb, Wkb, Wvb, qh, kh, vhT);
    flash_mfma<<<dim3(768), blk, 0, stream>>>(qh, kh, vhT, ctx, ctr);
    gemm_out<<<dim3(6, 32), blk, 0, stream>>>(ctx, Wob, (float*)d_out);
}